// Round 4
// baseline (218.405 us; speedup 1.0000x reference)
//
#include <hip/hip_runtime.h>

// Problem constants (fixed by the reference)
#define M_ROWS 8
#define K_DIM  8192
#define N_DIM  28672

#define BLOCK  256                 // 4 waves
#define NPW    4                   // n-rows per wave
#define NPB    16                  // n-rows per block
#define KC     512                 // K elements per staged chunk
#define NC     (K_DIM / KC)        // 16 chunks
#define SLOTS  ((NPB * KC) / (BLOCK * 4))   // 8 dwordx4 stage ops per thread

typedef __attribute__((ext_vector_type(4))) int   i32x4;
typedef __attribute__((ext_vector_type(4))) float f32x4;

// Stage one [NPB][KC] int32 tile of qweight into LDS via direct global->LDS DMA.
// LDS destination is linear (slot s -> base + s*16B), exactly lane order. [G5 §5]
__device__ __forceinline__ void stage_chunk(const int* __restrict__ qw,
                                            int* lds_base, int n0, int kc, int tid) {
#pragma unroll
    for (int i = 0; i < SLOTS; ++i) {
        const int e = (i * BLOCK + tid) * 4;            // int32 offset within tile
        const int row = e >> 9;                         // e / KC   (KC == 512)
        const int col = e & (KC - 1);                   // e % KC
        const int* g = qw + (size_t)(n0 + row) * K_DIM + kc + col;
        __builtin_amdgcn_global_load_lds(
            (const __attribute__((address_space(1))) void*)g,
            (__attribute__((address_space(3))) void*)(lds_base + e),
            16, 0, 0);
    }
}

__global__ __launch_bounds__(BLOCK) void w8a16_gemv_kernel(
    const float* __restrict__ x,      // [M,K] f32 (fp16 values upcast by harness)
    const int*   __restrict__ qw,     // [N,K] int32 (sign-extended int8)
    const float* __restrict__ scales, // [N]   f32
    const float* __restrict__ bias,   // [N]   f32
    float*       __restrict__ out)    // [M,N] f32
{
    __shared__ int qbuf[2][NPB][KC];   // 64 KiB -> 2 blocks/CU

    const int tid  = threadIdx.x;
    const int wave = tid >> 6;
    const int lane = tid & 63;
    const int n0   = blockIdx.x * NPB;

    float acc[NPW][M_ROWS];
#pragma unroll
    for (int j = 0; j < NPW; ++j)
#pragma unroll
        for (int m = 0; m < M_ROWS; ++m) acc[j][m] = 0.0f;

    // Prologue: stage chunk 0, drain, enter steady state.
    stage_chunk(qw, &qbuf[0][0][0], n0, 0, tid);
    __syncthreads();

    int cur = 0;
    for (int c = 0; c < NC; ++c) {
        const int kc = c * KC;

        // 1) x slice for this chunk -> registers FIRST (oldest vmem ops, so
        //    waiting on them never forces the stage loads below to drain).
        f32x4 xv[M_ROWS][KC / 256];
#pragma unroll
        for (int st = 0; st < KC / 256; ++st) {
            const int kk = kc + st * 256 + (lane << 2);
#pragma unroll
            for (int m = 0; m < M_ROWS; ++m)
                xv[m][st] = *reinterpret_cast<const f32x4*>(&x[(size_t)m * K_DIM + kk]);
        }

        // 2) issue next chunk's staging (stays in flight across the compute)
        if (c + 1 < NC)
            stage_chunk(qw, &qbuf[cur ^ 1][0][0], n0, kc + KC, tid);

        // 3) compute current chunk from LDS (lgkmcnt path only)
#pragma unroll
        for (int st = 0; st < KC / 256; ++st) {
            const int kk = st * 256 + (lane << 2);

            i32x4 q4[NPW];
#pragma unroll
            for (int j = 0; j < NPW; ++j)
                q4[j] = *reinterpret_cast<const i32x4*>(&qbuf[cur][wave * NPW + j][kk]);

            float qf[NPW][4];
#pragma unroll
            for (int j = 0; j < NPW; ++j) {
                qf[j][0] = (float)q4[j].x;
                qf[j][1] = (float)q4[j].y;
                qf[j][2] = (float)q4[j].z;
                qf[j][3] = (float)q4[j].w;
            }

#pragma unroll
            for (int m = 0; m < M_ROWS; ++m) {
                const f32x4 xm = xv[m][st];
#pragma unroll
                for (int j = 0; j < NPW; ++j) {
                    acc[j][m] += xm.x * qf[j][0];
                    acc[j][m] += xm.y * qf[j][1];
                    acc[j][m] += xm.z * qf[j][2];
                    acc[j][m] += xm.w * qf[j][3];
                }
            }
        }

        // 4) drain next chunk's loads + make buffer swap safe
        __syncthreads();
        cur ^= 1;
    }

    // Cross-lane reduction (64 lanes) for each of the 32 accumulators.
#pragma unroll
    for (int j = 0; j < NPW; ++j) {
#pragma unroll
        for (int m = 0; m < M_ROWS; ++m) {
            float v = acc[j][m];
#pragma unroll
            for (int off = 32; off > 0; off >>= 1)
                v += __shfl_xor(v, off, 64);
            acc[j][m] = v;
        }
    }

    if (lane == 0) {
#pragma unroll
        for (int j = 0; j < NPW; ++j) {
            const int n = n0 + wave * NPW + j;
            const float s = scales[n];
            const float b = bias[n];
#pragma unroll
            for (int m = 0; m < M_ROWS; ++m)
                out[(size_t)m * N_DIM + n] = s * acc[j][m] + b;
        }
    }
}

extern "C" void kernel_launch(void* const* d_in, const int* in_sizes, int n_in,
                              void* d_out, int out_size, void* d_ws, size_t ws_size,
                              hipStream_t stream) {
    const float* x      = (const float*)d_in[0];
    const int*   qw     = (const int*)d_in[1];
    const float* scales = (const float*)d_in[2];
    const float* bias   = (const float*)d_in[3];
    float*       out    = (float*)d_out;

    dim3 grid(N_DIM / NPB);   // 1792 blocks
    dim3 block(BLOCK);
    w8a16_gemv_kernel<<<grid, block, 0, stream>>>(x, qw, scales, bias, out);
}

// Round 5
// 204.749 us; speedup vs baseline: 1.0667x; 1.0667x over previous
//
#include <hip/hip_runtime.h>

// Problem constants (fixed by the reference)
#define M_ROWS 8
#define K_DIM  8192
#define N_DIM  28672

#define BLOCK  256           // 4 waves
#define NPW    4             // n-rows per wave
#define NPB    16            // n-rows per block
#define NSTEP  (K_DIM / 256) // 32 k-steps per wave (256 k per step)

typedef __attribute__((ext_vector_type(4))) int   i32x4;
typedef __attribute__((ext_vector_type(4))) float f32x4;

__global__ __launch_bounds__(BLOCK, 4) void w8a16_gemv_kernel(
    const float* __restrict__ x,      // [M,K] f32 (fp16 values upcast by harness)
    const int*   __restrict__ qw,     // [N,K] int32 (sign-extended int8)
    const float* __restrict__ scales, // [N]   f32
    const float* __restrict__ bias,   // [N]   f32
    float*       __restrict__ out)    // [M,N] f32
{
    const int tid  = threadIdx.x;
    const int wave = tid >> 6;
    const int lane = tid & 63;
    const int n0   = blockIdx.x * NPB + wave * NPW;
    const int kl   = lane << 2;       // 4 consecutive k per lane

    float acc[NPW][M_ROWS];
#pragma unroll
    for (int j = 0; j < NPW; ++j)
#pragma unroll
        for (int m = 0; m < M_ROWS; ++m) acc[j][m] = 0.0f;

    // Free-running k-sweep: no LDS, no barriers. q streams HBM (nontemporal,
    // zero reuse); x slices hit L1/L2 (256 KB total, shared by all blocks).
#pragma unroll 2
    for (int s = 0; s < NSTEP; ++s) {
        const int k = s * 256 + kl;

        i32x4 q4[NPW];
#pragma unroll
        for (int j = 0; j < NPW; ++j)
            q4[j] = __builtin_nontemporal_load(
                reinterpret_cast<const i32x4*>(qw + (size_t)(n0 + j) * K_DIM + k));

        float qf[NPW][4];
#pragma unroll
        for (int j = 0; j < NPW; ++j) {
            qf[j][0] = (float)q4[j].x;
            qf[j][1] = (float)q4[j].y;
            qf[j][2] = (float)q4[j].z;
            qf[j][3] = (float)q4[j].w;
        }

#pragma unroll
        for (int m = 0; m < M_ROWS; ++m) {
            const f32x4 xm = *reinterpret_cast<const f32x4*>(&x[(size_t)m * K_DIM + k]);
#pragma unroll
            for (int j = 0; j < NPW; ++j) {
                acc[j][m] += xm.x * qf[j][0];
                acc[j][m] += xm.y * qf[j][1];
                acc[j][m] += xm.z * qf[j][2];
                acc[j][m] += xm.w * qf[j][3];
            }
        }
    }

    // Cross-lane reduction (64 lanes) for each of the 32 accumulators.
#pragma unroll
    for (int j = 0; j < NPW; ++j) {
#pragma unroll
        for (int m = 0; m < M_ROWS; ++m) {
            float v = acc[j][m];
#pragma unroll
            for (int off = 32; off > 0; off >>= 1)
                v += __shfl_xor(v, off, 64);
            acc[j][m] = v;
        }
    }

    if (lane == 0) {
#pragma unroll
        for (int j = 0; j < NPW; ++j) {
            const int n = n0 + j;
            const float s = scales[n];
            const float b = bias[n];
#pragma unroll
            for (int m = 0; m < M_ROWS; ++m)
                out[(size_t)m * N_DIM + n] = s * acc[j][m] + b;
        }
    }
}

extern "C" void kernel_launch(void* const* d_in, const int* in_sizes, int n_in,
                              void* d_out, int out_size, void* d_ws, size_t ws_size,
                              hipStream_t stream) {
    const float* x      = (const float*)d_in[0];
    const int*   qw     = (const int*)d_in[1];
    const float* scales = (const float*)d_in[2];
    const float* bias   = (const float*)d_in[3];
    float*       out    = (float*)d_out;

    dim3 grid(N_DIM / NPB);   // 1792 blocks
    dim3 block(BLOCK);
    w8a16_gemv_kernel<<<grid, block, 0, stream>>>(x, qw, scales, bias, out);
}

// Round 6
// 194.960 us; speedup vs baseline: 1.1203x; 1.0502x over previous
//
#include <hip/hip_runtime.h>

// Problem constants (fixed by the reference)
#define M_ROWS 8
#define K_DIM  8192
#define N_DIM  28672

#define BLOCK  512                // 8 waves
#define NPW    2                  // n-rows per wave
#define NPB    16                 // n-rows per block (8 waves * 2)
#define KC     2048               // K elements per LDS x-chunk
#define NC     (K_DIM / KC)       // 4 chunks
#define STEPS  (KC / 256)         // 8 k-steps per chunk (256 k per step)

typedef __attribute__((ext_vector_type(4))) int   i32x4;
typedef __attribute__((ext_vector_type(4))) float f32x4;

__global__ __launch_bounds__(BLOCK, 4) void w8a16_gemv_kernel(
    const float* __restrict__ x,      // [M,K] f32 (fp16 values upcast by harness)
    const int*   __restrict__ qw,     // [N,K] int32 (sign-extended int8)
    const float* __restrict__ scales, // [N]   f32
    const float* __restrict__ bias,   // [N]   f32
    float*       __restrict__ out)    // [M,N] f32
{
    // x chunk in LDS: keeps the vmem (vmcnt) queue exclusively for q loads;
    // x reads ride the independent lgkm counter. 64 KiB -> 2 blocks/CU.
    __shared__ float xs[M_ROWS][KC];

    const int tid  = threadIdx.x;
    const int wave = tid >> 6;
    const int lane = tid & 63;
    const int n0   = blockIdx.x * NPB + wave * NPW;
    const int kl   = lane << 2;          // 4 consecutive k per lane

    float acc[NPW][M_ROWS];
#pragma unroll
    for (int j = 0; j < NPW; ++j)
#pragma unroll
        for (int m = 0; m < M_ROWS; ++m) acc[j][m] = 0.0f;

    for (int c = 0; c < NC; ++c) {
        const int kc = c * KC;

        __syncthreads();   // previous chunk's readers are done before overwrite
        // Stage x[0:8, kc:kc+KC] -> LDS, one row per iteration, VGPR-free DMA.
        // tid*16B is linear in lane order (global_load_lds dest requirement).
#pragma unroll
        for (int m = 0; m < M_ROWS; ++m) {
            const float* g = &x[(size_t)m * K_DIM + kc + (tid << 2)];
            __builtin_amdgcn_global_load_lds(
                (const __attribute__((address_space(1))) void*)g,
                (__attribute__((address_space(3))) void*)&xs[m][tid << 2],
                16, 0, 0);
        }
        __syncthreads();   // vmcnt(0)+barrier: stage complete for all waves

        // Inner: only q touches vmem -> q loads pipeline freely across steps.
#pragma unroll 4
        for (int s = 0; s < STEPS; ++s) {
            const int kk = s * 256 + kl;
            const int k  = kc + kk;

            i32x4 q4[NPW];
#pragma unroll
            for (int j = 0; j < NPW; ++j)
                q4[j] = __builtin_nontemporal_load(
                    reinterpret_cast<const i32x4*>(qw + (size_t)(n0 + j) * K_DIM + k));

            float qf[NPW][4];
#pragma unroll
            for (int j = 0; j < NPW; ++j) {
                qf[j][0] = (float)q4[j].x;
                qf[j][1] = (float)q4[j].y;
                qf[j][2] = (float)q4[j].z;
                qf[j][3] = (float)q4[j].w;
            }

#pragma unroll
            for (int m = 0; m < M_ROWS; ++m) {
                const f32x4 xm = *reinterpret_cast<const f32x4*>(&xs[m][kk]);
#pragma unroll
                for (int j = 0; j < NPW; ++j) {
                    acc[j][m] += xm.x * qf[j][0];
                    acc[j][m] += xm.y * qf[j][1];
                    acc[j][m] += xm.z * qf[j][2];
                    acc[j][m] += xm.w * qf[j][3];
                }
            }
        }
    }

    // Cross-lane reduction (64 lanes) for each accumulator.
#pragma unroll
    for (int j = 0; j < NPW; ++j) {
#pragma unroll
        for (int m = 0; m < M_ROWS; ++m) {
            float v = acc[j][m];
#pragma unroll
            for (int off = 32; off > 0; off >>= 1)
                v += __shfl_xor(v, off, 64);
            acc[j][m] = v;
        }
    }

    if (lane == 0) {
#pragma unroll
        for (int j = 0; j < NPW; ++j) {
            const int n = n0 + j;
            const float s = scales[n];
            const float b = bias[n];
#pragma unroll
            for (int m = 0; m < M_ROWS; ++m)
                out[(size_t)m * N_DIM + n] = s * acc[j][m] + b;
        }
    }
}

extern "C" void kernel_launch(void* const* d_in, const int* in_sizes, int n_in,
                              void* d_out, int out_size, void* d_ws, size_t ws_size,
                              hipStream_t stream) {
    const float* x      = (const float*)d_in[0];
    const int*   qw     = (const int*)d_in[1];
    const float* scales = (const float*)d_in[2];
    const float* bias   = (const float*)d_in[3];
    float*       out    = (float*)d_out;

    dim3 grid(N_DIM / NPB);   // 1792 blocks
    dim3 block(BLOCK);
    w8a16_gemv_kernel<<<grid, block, 0, stream>>>(x, qw, scales, bias, out);
}